// Round 1
// baseline (265.245 us; speedup 1.0000x reference)
//
#include <hip/hip_runtime.h>

#define NB 4
#define CDIM 256
#define HDIM 64
#define WDIM 64
#define LDIM 4096   // H*W
#define GG 4
#define CGD 64
#define PP 9
#define PWO 112

// ---------------------------------------------------------------------------
// Generic tiled fp32 GEMM:  C[m, c] = sum_k A[m,k] * Wm[c, k] + bias[c]
// A addressed per batch n:  A_KMAJOR ? An[k*ldA + m]  :  An[m*ldA + k]
// Output: OUT_T ? Cn[c*ldC + m] : Cn[m*ldC + c]
// Tile: 64(m) x 64(c), BK=16, 256 threads, 4x4 per thread. M must be %64, K %16.
// ---------------------------------------------------------------------------
template<bool A_KMAJOR, bool OUT_T>
__global__ __launch_bounds__(256) void gemm_kernel(
    const float* __restrict__ A, const float* __restrict__ Wm,
    const float* __restrict__ bias, float* __restrict__ Cout,
    int Nc, int Kd, int ldA, long aBatch, long cBatch, int ldC)
{
    const int n = blockIdx.z;
    const float* An = A + (size_t)n * aBatch;
    float* Cn = Cout + (size_t)n * cBatch;
    const int m0 = blockIdx.y * 64;
    const int c0 = blockIdx.x * 64;

    __shared__ float sa[16][64];
    __shared__ float sb[16][65];

    const int t = threadIdx.x;
    const int tx = t & 15, ty = t >> 4;

    float acc[4][4];
    #pragma unroll
    for (int i = 0; i < 4; ++i)
        #pragma unroll
        for (int j = 0; j < 4; ++j) acc[i][j] = 0.f;

    for (int k0 = 0; k0 < Kd; k0 += 16) {
        if (A_KMAJOR) {
            const int m = t & 63, kb = t >> 6;   // kb in 0..3
            #pragma unroll
            for (int i = 0; i < 4; ++i)
                sa[kb*4 + i][m] = An[(size_t)(k0 + kb*4 + i) * ldA + (m0 + m)];
        } else {
            const int kb = t & 15, mb = t >> 4;  // mb in 0..15
            #pragma unroll
            for (int i = 0; i < 4; ++i)
                sa[kb][mb + i*16] = An[(size_t)(m0 + mb + i*16) * ldA + (k0 + kb)];
        }
        {
            const int kb = t & 15, cb = t >> 4;
            #pragma unroll
            for (int i = 0; i < 4; ++i) {
                const int c = cb + i*16;
                sb[kb][c] = (c0 + c < Nc) ? Wm[(size_t)(c0 + c) * Kd + (k0 + kb)] : 0.f;
            }
        }
        __syncthreads();
        #pragma unroll
        for (int kk = 0; kk < 16; ++kk) {
            float av[4], bv[4];
            #pragma unroll
            for (int i = 0; i < 4; ++i) av[i] = sa[kk][ty*4 + i];
            #pragma unroll
            for (int j = 0; j < 4; ++j) bv[j] = sb[kk][tx*4 + j];
            #pragma unroll
            for (int i = 0; i < 4; ++i)
                #pragma unroll
                for (int j = 0; j < 4; ++j)
                    acc[i][j] = fmaf(av[i], bv[j], acc[i][j]);
        }
        __syncthreads();
    }

    #pragma unroll
    for (int j = 0; j < 4; ++j) {
        const int c = c0 + tx*4 + j;
        if (c < Nc) {
            const float bv = bias[c];
            #pragma unroll
            for (int i = 0; i < 4; ++i) {
                const int m = m0 + ty*4 + i;
                if (OUT_T) Cn[(size_t)c * ldC + m] = acc[i][j] + bv;
                else       Cn[(size_t)m * ldC + c] = acc[i][j] + bv;
            }
        }
    }
}

// ---------------------------------------------------------------------------
// Depthwise 3x3 conv, pad 1, stride 1.  x, out: [N, C, L] (L = H*W)
// ---------------------------------------------------------------------------
__global__ __launch_bounds__(256) void dwconv_kernel(
    const float* __restrict__ x, const float* __restrict__ wt,
    const float* __restrict__ bias, float* __restrict__ out)
{
    const int n = blockIdx.z, c = blockIdx.y;
    const int l = blockIdx.x * 256 + threadIdx.x;
    const int h = l >> 6, w = l & 63;
    const float* xn = x + ((size_t)n * CDIM + c) * LDIM;

    float wv[9];
    #pragma unroll
    for (int i = 0; i < 9; ++i) wv[i] = wt[c*9 + i];

    float s = bias[c];
    #pragma unroll
    for (int dy = -1; dy <= 1; ++dy) {
        const int hh = h + dy;
        if (hh < 0 || hh >= HDIM) continue;
        #pragma unroll
        for (int dx = -1; dx <= 1; ++dx) {
            const int ww = w + dx;
            if (ww < 0 || ww >= WDIM) continue;
            s = fmaf(xn[hh*WDIM + ww], wv[(dy+1)*3 + (dx+1)], s);
        }
    }
    out[((size_t)n * CDIM + c) * LDIM + l] = s;
}

// ---------------------------------------------------------------------------
// Deformable bilinear gather.
// om:  [N*L, 112]  (per (g,p): off_x, off_y, mask at g*27 + p*3 + {0,1,2})
// val: [N*L, 256]  (grouped: channel = g*64 + cg)
// acc: [N*L, 256]
// One block per (n,l); wave w handles group g=w; lane = cg.
// ---------------------------------------------------------------------------
__global__ __launch_bounds__(256) void gather_kernel(
    const float* __restrict__ om, const float* __restrict__ val,
    float* __restrict__ acc)
{
    const int bid = blockIdx.x;          // n*L + l
    const int n = bid >> 12;
    const int l = bid & (LDIM - 1);
    const int t = threadIdx.x;
    const int g = t >> 6, cg = t & 63;

    const float* omp = om + (size_t)bid * PWO + g * (PP * 3);
    const float* valn = val + (size_t)n * LDIM * CDIM;

    const float yb = (float)(l >> 6) - 1.f;   // PAD = 1
    const float xb = (float)(l & 63) - 1.f;

    float a = 0.f;
    #pragma unroll
    for (int p = 0; p < PP; ++p) {
        const float offx = omp[p*3 + 0];
        const float offy = omp[p*3 + 1];
        const float msk  = omp[p*3 + 2];
        const float py = yb + (float)(p / 3) + offy;
        const float px = xb + (float)(p % 3) + offx;
        const float y0f = floorf(py), x0f = floorf(px);
        const float fy = py - y0f, fx = px - x0f;
        const int iy0 = (int)y0f, ix0 = (int)x0f;
        #pragma unroll
        for (int dy = 0; dy < 2; ++dy) {
            const int iy = iy0 + dy;
            if (iy < 0 || iy >= HDIM) continue;
            const float wy = dy ? fy : 1.f - fy;
            #pragma unroll
            for (int dx = 0; dx < 2; ++dx) {
                const int ix = ix0 + dx;
                if (ix < 0 || ix >= WDIM) continue;
                const float wt = msk * wy * (dx ? fx : 1.f - fx);
                a = fmaf(wt, valn[(size_t)(iy*WDIM + ix) * CDIM + g*CGD + cg], a);
            }
        }
    }
    acc[(size_t)bid * CDIM + t] = a;
}

// ---------------------------------------------------------------------------
extern "C" void kernel_launch(void* const* d_in, const int* in_sizes, int n_in,
                              void* d_out, int out_size, void* d_ws, size_t ws_size,
                              hipStream_t stream) {
    const float* x      = (const float*)d_in[0];
    const float* dw_w   = (const float*)d_in[1];
    const float* dw_b   = (const float*)d_in[2];
    const float* pw_w   = (const float*)d_in[3];
    const float* pw_b   = (const float*)d_in[4];
    const float* pin_w  = (const float*)d_in[5];
    const float* pin_b  = (const float*)d_in[6];
    const float* pout_w = (const float*)d_in[7];
    const float* pout_b = (const float*)d_in[8];
    float* out = (float*)d_out;

    const size_t ML = (size_t)NB * LDIM;           // 16384
    float* ws  = (float*)d_ws;
    float* val = ws;                               // ML*256
    float* dwc = val + ML * CDIM;                  // ML*256
    float* omb = dwc + ML * CDIM;                  // ML*112
    float* acc = omb + ML * PWO;                   // ML*256

    // 1) val = pin(x):  A = x [C,L] per n, out [L, 256]
    gemm_kernel<true, false><<<dim3(4, 64, NB), 256, 0, stream>>>(
        x, pin_w, pin_b, val, CDIM, CDIM, LDIM,
        (long)CDIM * LDIM, (long)LDIM * CDIM, CDIM);

    // 2) depthwise conv
    dwconv_kernel<<<dim3(16, CDIM, NB), 256, 0, stream>>>(x, dw_w, dw_b, dwc);

    // 3) om = pw(dwc):  out [L, 112]
    gemm_kernel<true, false><<<dim3(2, 64, NB), 256, 0, stream>>>(
        dwc, pw_w, pw_b, omb, PWO, CDIM, LDIM,
        (long)CDIM * LDIM, (long)LDIM * PWO, PWO);

    // 4) deformable gather -> acc [N*L, 256]
    gather_kernel<<<dim3(NB * LDIM), 256, 0, stream>>>(omb, val, acc);

    // 5) out = pout(acc), transposed to [N, C, L]
    gemm_kernel<false, true><<<dim3(4, 64, NB), 256, 0, stream>>>(
        acc, pout_w, pout_b, out, CDIM, CDIM, CDIM,
        (long)LDIM * CDIM, (long)CDIM * LDIM, LDIM);
}

// Round 2
// 79.082 us; speedup vs baseline: 3.3540x; 3.3540x over previous
//
#include <hip/hip_runtime.h>

typedef unsigned short u16;
typedef short bf16x8 __attribute__((ext_vector_type(8)));
typedef u16 u16x8 __attribute__((ext_vector_type(8)));
typedef float f32x4 __attribute__((ext_vector_type(4)));

#define K_DIM 256
#define L_DIM 4096
#define NBATCH 4

static __device__ __forceinline__ u16 f2bf(float f) {
    unsigned u = __float_as_uint(f);
    unsigned r = (u + 0x7FFFu + ((u >> 16) & 1u)) >> 16;
    return (u16)r;
}
static __device__ __forceinline__ float bf2f(u16 v) {
    return __uint_as_float(((unsigned)v) << 16);
}

#define GLOAD16(g, l) __builtin_amdgcn_global_load_lds( \
    (const __attribute__((address_space(1))) void*)(g), \
    (__attribute__((address_space(3))) void*)(l), 16, 0, 0)

// ---------------------------------------------------------------------------
// Weight cast: pin_w[256x256], pw_w[112x256] (pad->128 rows), pout_w[256x256]
// ---------------------------------------------------------------------------
__global__ __launch_bounds__(256) void wconv_kernel(
    const float* __restrict__ pin_w, const float* __restrict__ pw_w,
    const float* __restrict__ pout_w, u16* __restrict__ pin_wb,
    u16* __restrict__ pw_wb, u16* __restrict__ pout_wb)
{
    int i = blockIdx.x * 256 + threadIdx.x;
    for (int k = i; k < 163840; k += 40960) {
        if (k < 65536) pin_wb[k] = f2bf(pin_w[k]);
        else if (k < 98304) {
            int j = k - 65536;
            pw_wb[j] = ((j >> 8) < 112) ? f2bf(pw_w[j]) : (u16)0;
        } else {
            int j = k - 98304;
            pout_wb[j] = f2bf(pout_w[j]);
        }
    }
}

// ---------------------------------------------------------------------------
// Prep: per (n, h, c-tile of 64): depthwise 3x3 conv + transpose + bf16 cast.
// Produces xb_t[NL, 256] (x transposed) and dwc_t[NL, 256] (conv transposed).
// ---------------------------------------------------------------------------
__global__ __launch_bounds__(256) void prep_kernel(
    const float* __restrict__ x, const float* __restrict__ dw_w,
    const float* __restrict__ dw_b, u16* __restrict__ xb_t,
    u16* __restrict__ dwc_t)
{
    __shared__ u16 tx_[64][66];
    __shared__ u16 td_[64][66];
    const int c0 = blockIdx.x * 64, h = blockIdx.y, n = blockIdx.z;
    const int t = threadIdx.x, w = t & 63, cq = t >> 6;
    const float* xn = x + (size_t)n * 256 * L_DIM;
    const int wm = (w > 0) ? w - 1 : 0;
    const int wp = (w < 63) ? w + 1 : 63;
    const float lv = (w > 0) ? 1.f : 0.f;
    const float rv = (w < 63) ? 1.f : 0.f;

    for (int i = 0; i < 16; ++i) {
        const int cl = i * 4 + cq, c = c0 + cl;
        const float* xc = xn + (size_t)c * L_DIM;
        const float* w9 = dw_w + c * 9;
        float s = dw_b[c];
        #pragma unroll
        for (int dy = 0; dy < 3; ++dy) {
            const int hh = h + dy - 1;
            if (hh < 0 || hh > 63) continue;   // block-uniform branch
            const float* row = xc + hh * 64;
            s = fmaf(row[wm] * lv, w9[dy*3 + 0], s);
            s = fmaf(row[w],       w9[dy*3 + 1], s);
            s = fmaf(row[wp] * rv, w9[dy*3 + 2], s);
        }
        tx_[w][cl] = f2bf(xc[h*64 + w]);
        td_[w][cl] = f2bf(s);
    }
    __syncthreads();
    const int cc = t & 63;
    for (int j = 0; j < 16; ++j) {
        const int wl = j * 4 + cq;
        const size_t o = ((size_t)n * L_DIM + h * 64 + wl) * 256 + c0 + cc;
        xb_t[o]  = tx_[wl][cc];
        dwc_t[o] = td_[wl][cc];
    }
}

// ---------------------------------------------------------------------------
// bf16 MFMA GEMM: C[m,c] = sum_k A[m,k]*B[c,k] + bias
// A [*,256] row-major bf16, B [*,256] row-major bf16 (i.e. W as stored).
// Tile 128x128, BK=32, 256 thr (4 waves 2x2), 2-buffer single-barrier loop.
// ---------------------------------------------------------------------------
template<bool OUT_BF16, bool BIAS_ROW>
__global__ __launch_bounds__(256) void gemm_mfma(
    const u16* __restrict__ A, long aBatch,
    const u16* __restrict__ B, long bBatch,
    const float* __restrict__ bias,
    void* __restrict__ Cptr, long cBatch, int ldC, int Ncols)
{
    __shared__ u16 lds[16384];   // 32 KB: two 16KB buffers (A 8K | B 8K)
    const int z = blockIdx.z;
    const u16* Ag = A + (size_t)aBatch * z;
    const u16* Bg = B + (size_t)bBatch * z;
    const int m0 = blockIdx.y * 128, n0 = blockIdx.x * 128;
    const int t = threadIdx.x;
    const int wave = t >> 6, lane = t & 63;
    const int lr = lane & 15, lk = lane >> 4;
    const int wr = wave >> 1, wc = wave & 1;
    const int wbase = wave << 10;              // bytes, wave-uniform

    const int srow = t >> 2;
    const int scol = (t & 3) * 8;
    const u16* ga0 = Ag + (size_t)(m0 + srow)      * K_DIM + scol;
    const u16* ga1 = Ag + (size_t)(m0 + 64 + srow) * K_DIM + scol;
    const u16* gb0 = Bg + (size_t)(n0 + srow)      * K_DIM + scol;
    const u16* gb1 = Bg + (size_t)(n0 + 64 + srow) * K_DIM + scol;

    f32x4 acc[4][4];
    #pragma unroll
    for (int m = 0; m < 4; ++m)
        #pragma unroll
        for (int n = 0; n < 4; ++n) acc[m][n] = (f32x4){0.f, 0.f, 0.f, 0.f};

    auto stage = [&](int b, int kt) {
        const int ko = kt * 32;
        char* base = (char*)lds + b * 16384 + wbase;
        GLOAD16(ga0 + ko, base);
        GLOAD16(ga1 + ko, base + 4096);
        GLOAD16(gb0 + ko, base + 8192);
        GLOAD16(gb1 + ko, base + 12288);
    };

    stage(0, 0);
    asm volatile("s_waitcnt vmcnt(0)" ::: "memory");
    __syncthreads();

    for (int kt = 0; kt < 8; ++kt) {
        const int cur = kt & 1;
        if (kt < 7) stage(cur ^ 1, kt + 1);
        const char* la = (const char*)lds + cur * 16384;
        const char* lb = la + 8192;
        bf16x8 af[4], bfr[4];
        #pragma unroll
        for (int m = 0; m < 4; ++m)
            af[m] = *(const bf16x8*)(la + ((wr*64 + m*16 + lr) * 32 + lk * 8) * 2);
        #pragma unroll
        for (int n = 0; n < 4; ++n)
            bfr[n] = *(const bf16x8*)(lb + ((wc*64 + n*16 + lr) * 32 + lk * 8) * 2);
        #pragma unroll
        for (int m = 0; m < 4; ++m)
            #pragma unroll
            for (int n = 0; n < 4; ++n)
                acc[m][n] = __builtin_amdgcn_mfma_f32_16x16x32_bf16(
                    af[m], bfr[n], acc[m][n], 0, 0, 0);
        asm volatile("s_waitcnt vmcnt(0)" ::: "memory");
        __syncthreads();
    }

    #pragma unroll
    for (int m = 0; m < 4; ++m) {
        #pragma unroll
        for (int n = 0; n < 4; ++n) {
            const int col = n0 + wc*64 + n*16 + lr;
            if (col < Ncols) {
                #pragma unroll
                for (int r = 0; r < 4; ++r) {
                    const int row = m0 + wr*64 + m*16 + lk*4 + r;
                    const float o = acc[m][n][r] + (BIAS_ROW ? bias[row] : bias[col]);
                    const size_t off = (size_t)cBatch * z + (size_t)row * ldC + col;
                    if (OUT_BF16) ((u16*)Cptr)[off] = f2bf(o);
                    else          ((float*)Cptr)[off] = o;
                }
            }
        }
    }
}

// ---------------------------------------------------------------------------
// Deformable bilinear gather, branchless, bf16 val -> bf16 acc.
// Wave = 2 positions x 4 groups x 8 lanes; each lane owns 8 channels (16B).
// ---------------------------------------------------------------------------
__global__ __launch_bounds__(256) void gather_kernel(
    const float* __restrict__ om, const u16* __restrict__ val,
    u16* __restrict__ accb)
{
    const int t = threadIdx.x, lane = t & 63;
    const int pos = blockIdx.x * 8 + (t >> 6) * 2 + (lane >> 5);
    const int g = (lane >> 3) & 3, ch = (lane & 7) * 8;
    const int n = pos >> 12, l = pos & 4095;
    const float* omp = om + (size_t)pos * 112 + g * 27;
    const u16* vb = val + ((size_t)n * L_DIM) * 256 + g * 64 + ch;
    const float yb = (float)(l >> 6) - 1.f;
    const float xb = (float)(l & 63) - 1.f;

    float a[8];
    #pragma unroll
    for (int j = 0; j < 8; ++j) a[j] = 0.f;

    #pragma unroll
    for (int p = 0; p < 9; ++p) {
        const float ox = omp[p*3 + 0];
        const float oy = omp[p*3 + 1];
        const float mk = omp[p*3 + 2];
        const float py = yb + (float)(p / 3) + oy;
        const float px = xb + (float)(p % 3) + ox;
        const float y0 = floorf(py), x0 = floorf(px);
        const float fy = py - y0, fx = px - x0;
        const int iy0 = (int)y0, ix0 = (int)x0;
        #pragma unroll
        for (int q = 0; q < 4; ++q) {
            const int dy = q >> 1, dx = q & 1;
            const int iy = iy0 + dy, ix = ix0 + dx;
            const bool vld = ((unsigned)iy < 64u) & ((unsigned)ix < 64u);
            float wgt = mk * (dy ? fy : 1.f - fy) * (dx ? fx : 1.f - fx);
            wgt = vld ? wgt : 0.f;
            const int iyc = min(max(iy, 0), 63);
            const int ixc = min(max(ix, 0), 63);
            const u16x8 v = *(const u16x8*)(vb + (size_t)(iyc * 64 + ixc) * 256);
            #pragma unroll
            for (int j = 0; j < 8; ++j)
                a[j] = fmaf(wgt, bf2f(v[j]), a[j]);
        }
    }
    u16x8 o;
    #pragma unroll
    for (int j = 0; j < 8; ++j) o[j] = f2bf(a[j]);
    *(u16x8*)(accb + (size_t)pos * 256 + g * 64 + ch) = o;
}

// ---------------------------------------------------------------------------
extern "C" void kernel_launch(void* const* d_in, const int* in_sizes, int n_in,
                              void* d_out, int out_size, void* d_ws, size_t ws_size,
                              hipStream_t stream) {
    const float* x      = (const float*)d_in[0];
    const float* dw_w   = (const float*)d_in[1];
    const float* dw_b   = (const float*)d_in[2];
    const float* pw_w   = (const float*)d_in[3];
    const float* pw_b   = (const float*)d_in[4];
    const float* pin_w  = (const float*)d_in[5];
    const float* pin_b  = (const float*)d_in[6];
    const float* pout_w = (const float*)d_in[7];
    const float* pout_b = (const float*)d_in[8];
    float* out = (float*)d_out;

    char* ws = (char*)d_ws;
    u16*   xb_t    = (u16*)ws;                      //  8,388,608
    u16*   dwc_t   = (u16*)(ws + 8388608);          //  8,388,608
    u16*   val_b   = (u16*)(ws + 16777216);         //  8,388,608
    u16*   acc_b   = (u16*)(ws + 25165824);         //  8,388,608
    float* omb     = (float*)(ws + 33554432);       //  7,340,032
    u16*   pin_wb  = (u16*)(ws + 40894464);         //    131,072
    u16*   pw_wb   = (u16*)(ws + 41025536);         //     65,536 (128 rows)
    u16*   pout_wb = (u16*)(ws + 41091072);         //    131,072

    // weights -> bf16 (pw padded to 128 rows)
    wconv_kernel<<<160, 256, 0, stream>>>(pin_w, pw_w, pout_w,
                                          pin_wb, pw_wb, pout_wb);
    // x transpose-cast + depthwise conv transpose-cast
    prep_kernel<<<dim3(4, 64, NBATCH), 256, 0, stream>>>(x, dw_w, dw_b, xb_t, dwc_t);

    // val = pin(x):  [16384,256] x [256,256]^T -> bf16 [16384,256]
    gemm_mfma<true, false><<<dim3(2, 128, 1), 256, 0, stream>>>(
        xb_t, 0, pin_wb, 0, pin_b, val_b, 0, 256, 256);

    // om = pw(dwc): [16384,256] x [112,256]^T -> fp32 [16384,112]
    gemm_mfma<false, false><<<dim3(1, 128, 1), 256, 0, stream>>>(
        dwc_t, 0, pw_wb, 0, pw_b, omb, 0, 112, 112);

    // deformable gather -> bf16 [16384,256]
    gather_kernel<<<2048, 256, 0, stream>>>(omb, val_b, acc_b);

    // out^T = pout_w x acc^T: per n: [256,256] x [4096,256]^T -> fp32 [256,4096]
    gemm_mfma<false, true><<<dim3(32, 2, NBATCH), 256, 0, stream>>>(
        pout_wb, 0, acc_b, (long)L_DIM * 256, pout_b,
        out, (long)256 * L_DIM, L_DIM, L_DIM);
}

// Round 3
// 71.173 us; speedup vs baseline: 3.7268x; 1.1111x over previous
//
#include <hip/hip_runtime.h>

typedef unsigned short u16;
typedef short bf16x8 __attribute__((ext_vector_type(8)));
typedef u16 u16x8 __attribute__((ext_vector_type(8)));
typedef float f32x4 __attribute__((ext_vector_type(4)));

#define K_DIM 256
#define L_DIM 4096
#define NBATCH 4

static __device__ __forceinline__ u16 f2bf(float f) {
    unsigned u = __float_as_uint(f);
    unsigned r = (u + 0x7FFFu + ((u >> 16) & 1u)) >> 16;
    return (u16)r;
}
static __device__ __forceinline__ float bf2f(u16 v) {
    return __uint_as_float(((unsigned)v) << 16);
}

#define GLOAD16(g, l) __builtin_amdgcn_global_load_lds( \
    (const __attribute__((address_space(1))) void*)(g), \
    (__attribute__((address_space(3))) void*)(l), 16, 0, 0)

// ---------------------------------------------------------------------------
// K1: depthwise 3x3 conv + transpose + bf16 cast; weight casts folded in as
// extra blocks (blockIdx.x == 4).
// Produces xb_t[NL,256], dwc_t[NL,256], and bf16 weights.
// ---------------------------------------------------------------------------
__global__ __launch_bounds__(256) void prep_kernel(
    const float* __restrict__ x, const float* __restrict__ dw_w,
    const float* __restrict__ dw_b, const float* __restrict__ pin_w,
    const float* __restrict__ pw_w, const float* __restrict__ pout_w,
    u16* __restrict__ xb_t, u16* __restrict__ dwc_t,
    u16* __restrict__ pin_wb, u16* __restrict__ pw_wb,
    u16* __restrict__ pout_wb)
{
    if (blockIdx.x == 4) {                      // weight-cast blocks
        if (blockIdx.z != 0) return;
        const int end = (blockIdx.y + 1) * 2560;
        for (int k = blockIdx.y * 2560 + threadIdx.x; k < end; k += 256) {
            if (k < 65536) pin_wb[k] = f2bf(pin_w[k]);
            else if (k < 98304) {
                int j = k - 65536;
                pw_wb[j] = ((j >> 8) < 112) ? f2bf(pw_w[j]) : (u16)0;
            } else {
                int j = k - 98304;
                pout_wb[j] = f2bf(pout_w[j]);
            }
        }
        return;
    }

    __shared__ u16 tx_[64][66];
    __shared__ u16 td_[64][66];
    const int c0 = blockIdx.x * 64, h = blockIdx.y, n = blockIdx.z;
    const int t = threadIdx.x, w = t & 63, cq = t >> 6;
    const float* xn = x + (size_t)n * 256 * L_DIM;
    const int wm = (w > 0) ? w - 1 : 0;
    const int wp = (w < 63) ? w + 1 : 63;
    const float lv = (w > 0) ? 1.f : 0.f;
    const float rv = (w < 63) ? 1.f : 0.f;

    for (int i = 0; i < 16; ++i) {
        const int cl = i * 4 + cq, c = c0 + cl;
        const float* xc = xn + (size_t)c * L_DIM;
        const float* w9 = dw_w + c * 9;
        float s = dw_b[c];
        #pragma unroll
        for (int dy = 0; dy < 3; ++dy) {
            const int hh = h + dy - 1;
            if (hh < 0 || hh > 63) continue;   // block-uniform branch
            const float* row = xc + hh * 64;
            s = fmaf(row[wm] * lv, w9[dy*3 + 0], s);
            s = fmaf(row[w],       w9[dy*3 + 1], s);
            s = fmaf(row[wp] * rv, w9[dy*3 + 2], s);
        }
        tx_[w][cl] = f2bf(xc[h*64 + w]);
        td_[w][cl] = f2bf(s);
    }
    __syncthreads();
    const int cc = t & 63;
    for (int j = 0; j < 16; ++j) {
        const int wl = j * 4 + cq;
        const size_t o = ((size_t)n * L_DIM + h * 64 + wl) * 256 + c0 + cc;
        xb_t[o]  = tx_[wl][cc];
        dwc_t[o] = td_[wl][cc];
    }
}

// ---------------------------------------------------------------------------
// K2: pin + pw GEMMs in one dispatch.
// C[m,c] = sum_k A[m,k]*B[c,k] + bias[c]; A,B row-major bf16 (K=256).
// Tile 128x128, BK=32, 256 thr (4 waves 2x2), 2-buffer single-barrier loop.
// blockIdx.x: 0,1 -> pin col-tiles (out bf16 val_b); 2 -> pw (out fp32 omb).
// ---------------------------------------------------------------------------
__global__ __launch_bounds__(256) void gemm_dual(
    const u16* __restrict__ xb_t, const u16* __restrict__ dwc_t,
    const u16* __restrict__ pin_wb, const u16* __restrict__ pw_wb,
    const float* __restrict__ pin_b, const float* __restrict__ pw_b,
    u16* __restrict__ val_b, float* __restrict__ omb)
{
    __shared__ u16 lds[16384];   // 32 KB: two 16KB buffers (A 8K | B 8K)
    const int bx = blockIdx.x;
    const bool isPw = (bx == 2);
    const u16* Ag = isPw ? dwc_t : xb_t;
    const u16* Bg = isPw ? pw_wb : pin_wb;
    const float* bias = isPw ? pw_b : pin_b;
    const int n0 = isPw ? 0 : bx * 128;
    const int Ncols = isPw ? 112 : 256;
    const int ldC = isPw ? 112 : 256;
    const int m0 = blockIdx.y * 128;

    const int t = threadIdx.x;
    const int wave = t >> 6, lane = t & 63;
    const int lr = lane & 15, lk = lane >> 4;
    const int wr = wave >> 1, wc = wave & 1;
    const int wbase = wave << 10;

    const int srow = t >> 2;
    const int scol = (t & 3) * 8;
    const u16* ga0 = Ag + (size_t)(m0 + srow)      * K_DIM + scol;
    const u16* ga1 = Ag + (size_t)(m0 + 64 + srow) * K_DIM + scol;
    const u16* gb0 = Bg + (size_t)(n0 + srow)      * K_DIM + scol;
    const u16* gb1 = Bg + (size_t)(n0 + 64 + srow) * K_DIM + scol;

    f32x4 acc[4][4];
    #pragma unroll
    for (int m = 0; m < 4; ++m)
        #pragma unroll
        for (int n = 0; n < 4; ++n) acc[m][n] = (f32x4){0.f, 0.f, 0.f, 0.f};

    auto stage = [&](int b, int kt) {
        const int ko = kt * 32;
        char* base = (char*)lds + b * 16384 + wbase;
        GLOAD16(ga0 + ko, base);
        GLOAD16(ga1 + ko, base + 4096);
        GLOAD16(gb0 + ko, base + 8192);
        GLOAD16(gb1 + ko, base + 12288);
    };

    stage(0, 0);
    asm volatile("s_waitcnt vmcnt(0)" ::: "memory");
    __syncthreads();

    for (int kt = 0; kt < 8; ++kt) {
        const int cur = kt & 1;
        if (kt < 7) stage(cur ^ 1, kt + 1);
        const char* la = (const char*)lds + cur * 16384;
        const char* lb = la + 8192;
        bf16x8 af[4], bfr[4];
        #pragma unroll
        for (int m = 0; m < 4; ++m)
            af[m] = *(const bf16x8*)(la + ((wr*64 + m*16 + lr) * 32 + lk * 8) * 2);
        #pragma unroll
        for (int n = 0; n < 4; ++n)
            bfr[n] = *(const bf16x8*)(lb + ((wc*64 + n*16 + lr) * 32 + lk * 8) * 2);
        #pragma unroll
        for (int m = 0; m < 4; ++m)
            #pragma unroll
            for (int n = 0; n < 4; ++n)
                acc[m][n] = __builtin_amdgcn_mfma_f32_16x16x32_bf16(
                    af[m], bfr[n], acc[m][n], 0, 0, 0);
        asm volatile("s_waitcnt vmcnt(0)" ::: "memory");
        __syncthreads();
    }

    #pragma unroll
    for (int m = 0; m < 4; ++m) {
        #pragma unroll
        for (int n = 0; n < 4; ++n) {
            const int col = n0 + wc*64 + n*16 + lr;
            if (col < Ncols) {
                const float bv = bias[col];
                #pragma unroll
                for (int r = 0; r < 4; ++r) {
                    const int row = m0 + wr*64 + m*16 + lk*4 + r;
                    const float o = acc[m][n][r] + bv;
                    const size_t off = (size_t)row * ldC + col;
                    if (isPw) omb[off] = o;
                    else      val_b[off] = f2bf(o);
                }
            }
        }
    }
}

// ---------------------------------------------------------------------------
// K3: fused deformable gather + output projection.
// Block = 64 positions (all in one n), 512 threads (8 waves).
// Phase A: gather -> LDS bf16 tile sacc[64][264] (padded pitch).
// Phase B: out[c, pos] = sum_k pout_w[c,k] * sacc[pos,k] + pout_b[c],
//          written transposed to out[N, 256, 4096] fp32.
// ---------------------------------------------------------------------------
__global__ __launch_bounds__(512) void gather_pout(
    const float* __restrict__ om, const u16* __restrict__ val,
    const u16* __restrict__ pout_wb, const float* __restrict__ pout_b,
    float* __restrict__ out)
{
    __shared__ u16 sacc[64][264];
    const int blk = blockIdx.x;            // 0..255
    const int n = blk >> 6;
    const int l0 = (blk & 63) * 64;
    const int t = threadIdx.x;

    // ---- Phase A: deformable bilinear gather into LDS ----
    {
        const int pidx = t >> 5, g = (t >> 3) & 3, co = t & 7;
        const u16* vb = val + (size_t)n * L_DIM * 256 + g * 64 + co * 8;
        #pragma unroll
        for (int i = 0; i < 4; ++i) {
            const int pl = i * 16 + pidx;           // local position 0..63
            const int l = l0 + pl;
            const float* omp = om + ((size_t)n * L_DIM + l) * 112 + g * 27;
            const float yb = (float)(l >> 6) - 1.f;
            const float xb = (float)(l & 63) - 1.f;

            float a[8];
            #pragma unroll
            for (int j = 0; j < 8; ++j) a[j] = 0.f;

            #pragma unroll
            for (int p = 0; p < 9; ++p) {
                const float ox = omp[p*3 + 0];
                const float oy = omp[p*3 + 1];
                const float mk = omp[p*3 + 2];
                const float py = yb + (float)(p / 3) + oy;
                const float px = xb + (float)(p % 3) + ox;
                const float y0 = floorf(py), x0 = floorf(px);
                const float fy = py - y0, fx = px - x0;
                const int iy0 = (int)y0, ix0 = (int)x0;
                #pragma unroll
                for (int q = 0; q < 4; ++q) {
                    const int dy = q >> 1, dx = q & 1;
                    const int iy = iy0 + dy, ix = ix0 + dx;
                    const bool vld = ((unsigned)iy < 64u) & ((unsigned)ix < 64u);
                    float wgt = mk * (dy ? fy : 1.f - fy) * (dx ? fx : 1.f - fx);
                    wgt = vld ? wgt : 0.f;
                    const int iyc = min(max(iy, 0), 63);
                    const int ixc = min(max(ix, 0), 63);
                    const u16x8 v = *(const u16x8*)(vb + (size_t)(iyc * 64 + ixc) * 256);
                    #pragma unroll
                    for (int j = 0; j < 8; ++j)
                        a[j] = fmaf(wgt, bf2f(v[j]), a[j]);
                }
            }
            u16x8 o;
            #pragma unroll
            for (int j = 0; j < 8; ++j) o[j] = f2bf(a[j]);
            *(u16x8*)(&sacc[pl][g * 64 + co * 8]) = o;
        }
    }
    __syncthreads();

    // ---- Phase B: pout GEMM (A = pout_wb from L2, B = LDS tile) ----
    const int wave = t >> 6, lane = t & 63;
    const int lr = lane & 15, lk = lane >> 4;
    const int wr = wave >> 1, wc = wave & 1;     // wr: c-block/64, wc: pos-block/32

    f32x4 acc[4][2];
    #pragma unroll
    for (int m = 0; m < 4; ++m)
        #pragma unroll
        for (int nn = 0; nn < 2; ++nn) acc[m][nn] = (f32x4){0.f, 0.f, 0.f, 0.f};

    #pragma unroll
    for (int kt = 0; kt < 8; ++kt) {
        bf16x8 af[4], bfr[2];
        #pragma unroll
        for (int m = 0; m < 4; ++m)
            af[m] = *(const bf16x8*)(pout_wb +
                (size_t)(wr*64 + m*16 + lr) * K_DIM + kt*32 + lk*8);
        #pragma unroll
        for (int nn = 0; nn < 2; ++nn)
            bfr[nn] = *(const bf16x8*)(&sacc[wc*32 + nn*16 + lr][kt*32 + lk*8]);
        #pragma unroll
        for (int m = 0; m < 4; ++m)
            #pragma unroll
            for (int nn = 0; nn < 2; ++nn)
                acc[m][nn] = __builtin_amdgcn_mfma_f32_16x16x32_bf16(
                    af[m], bfr[nn], acc[m][nn], 0, 0, 0);
    }

    float* outn = out + (size_t)n * 256 * L_DIM;
    #pragma unroll
    for (int m = 0; m < 4; ++m) {
        #pragma unroll
        for (int nn = 0; nn < 2; ++nn) {
            const int col = l0 + wc*32 + nn*16 + lr;
            #pragma unroll
            for (int r = 0; r < 4; ++r) {
                const int row = wr*64 + m*16 + lk*4 + r;
                outn[(size_t)row * L_DIM + col] = acc[m][nn][r] + pout_b[row];
            }
        }
    }
}

// ---------------------------------------------------------------------------
extern "C" void kernel_launch(void* const* d_in, const int* in_sizes, int n_in,
                              void* d_out, int out_size, void* d_ws, size_t ws_size,
                              hipStream_t stream) {
    const float* x      = (const float*)d_in[0];
    const float* dw_w   = (const float*)d_in[1];
    const float* dw_b   = (const float*)d_in[2];
    const float* pw_w   = (const float*)d_in[3];
    const float* pw_b   = (const float*)d_in[4];
    const float* pin_w  = (const float*)d_in[5];
    const float* pin_b  = (const float*)d_in[6];
    const float* pout_w = (const float*)d_in[7];
    const float* pout_b = (const float*)d_in[8];
    float* out = (float*)d_out;

    char* ws = (char*)d_ws;
    u16*   xb_t    = (u16*)ws;                      //  8,388,608
    u16*   dwc_t   = (u16*)(ws + 8388608);          //  8,388,608
    u16*   val_b   = (u16*)(ws + 16777216);         //  8,388,608
    float* omb     = (float*)(ws + 25165824);       //  7,340,032
    u16*   pin_wb  = (u16*)(ws + 32505856);         //    131,072
    u16*   pw_wb   = (u16*)(ws + 32636928);         //     65,536 (128 rows)
    u16*   pout_wb = (u16*)(ws + 32702464);         //    131,072

    // K1: depthwise conv + transpose-cast + weight casts
    prep_kernel<<<dim3(5, 64, NBATCH), 256, 0, stream>>>(
        x, dw_w, dw_b, pin_w, pw_w, pout_w,
        xb_t, dwc_t, pin_wb, pw_wb, pout_wb);

    // K2: val = pin(x) [bf16], om = pw(dwc) [fp32]
    gemm_dual<<<dim3(3, 128), 256, 0, stream>>>(
        xb_t, dwc_t, pin_wb, pw_wb, pin_b, pw_b, val_b, omb);

    // K3: deformable gather + pout projection, transposed fp32 output
    gather_pout<<<dim3(256), 512, 0, stream>>>(
        omb, val_b, pout_wb, pout_b, out);
}